// Round 5
// baseline (65.662 us; speedup 1.0000x reference)
//
#include <hip/hip_runtime.h>

// ConvexReLUCNN: B=512, C=3, H=W=64, KERNEL=3
//   K=27, L=62*62=3844, M=512, O=10
#define M_NEUR 512
#define ODIM   10
#define HO     62
#define LDIM   3844
#define CHW    12288
#define BATCH  512
#define KO     270
#define KOP    272                    // ko padded to 4*68
#define NPART  4                      // m-split partials
#define TPSTR  ((size_t)KO * LDIM)    // per-partial stride (floats)

// ---------------------------------------------------------------------------
// K0: pdP[m][ko] = v[m][ko] - w[m][ko]  (ko = k*10+o), zero-pad ko 270..271.
// ---------------------------------------------------------------------------
__global__ __launch_bounds__(256)
void pd_kernel(const float* __restrict__ v, const float* __restrict__ w,
               float* __restrict__ pdP) {
    int idx = blockIdx.x * 256 + threadIdx.x;
    if (idx >= M_NEUR * KOP) return;
    int m  = idx / KOP;
    int ko = idx - m * KOP;
    pdP[idx] = (ko < KO) ? (v[m * KO + ko] - w[m * KO + ko]) : 0.f;
}

// ---------------------------------------------------------------------------
// K1: Tp[mc][ko][n] = sum_{m in chunk mc} pdP[m][ko] * G[m][n]
// Unit = 1 wave: 256 n (lane*4, float4) x 4 ko (wave-broadcast float4) x 128 m.
// Block = 4 waves = 4 consecutive ko-tiles of the same (n-tile, mc).
// Grid 1088 = 8 xcd x 8 groups x 17 blocks; all 17 blocks sharing a G-panel
// (same n-tile, mc) land on one XCD -> G HBM-fetched once, L2 re-served.
// All operands via vector-memory path (deep vmcnt pipelining); no LDS/s_load.
// ---------------------------------------------------------------------------
__global__ __launch_bounds__(256, 4)
void t_gemm_kernel(const float* __restrict__ G,
                   const float* __restrict__ pdP,
                   float* __restrict__ Tp) {
    const int bid  = blockIdx.x;
    const int xcd  = bid & 7;
    const int s    = bid >> 3;            // 0..135
    const int q    = s / 17;              // 0..7
    const int r    = s - q * 17;          // 0..16
    const int grp  = xcd + 8 * q;         // 0..63
    const int tile = grp >> 2;            // n-tile 0..15 (256 n each)
    const int mc   = grp & 3;             // m-chunk 0..3 (128 m each)
    const int wv   = threadIdx.x >> 6;    // 0..3
    const int lane = threadIdx.x & 63;
    const int jt   = 4 * r + wv;          // ko-tile 0..67
    const int ko0  = jt * 4;
    const int m0   = mc * 128;

    const int nb   = tile * 256 + lane * 4;
    const bool nok = (nb < LDIM);
    const int nbc  = nok ? nb : 0;

    const float4* Gp = reinterpret_cast<const float4*>(G + (size_t)m0 * LDIM + nbc);
    const float4* Pp = reinterpret_cast<const float4*>(pdP + (size_t)m0 * KOP + ko0);
    const int GS4 = LDIM / 4;   // 961
    const int PS4 = KOP / 4;    // 68

    float acc[4][4];
#pragma unroll
    for (int j = 0; j < 4; ++j)
#pragma unroll
        for (int nn = 0; nn < 4; ++nn) acc[j][nn] = 0.f;

#pragma unroll 4
    for (int mi = 0; mi < 128; ++mi) {
        float4 gv = Gp[(size_t)mi * GS4];
        float4 pv = Pp[(size_t)mi * PS4];
        acc[0][0] += pv.x * gv.x;  acc[0][1] += pv.x * gv.y;
        acc[0][2] += pv.x * gv.z;  acc[0][3] += pv.x * gv.w;
        acc[1][0] += pv.y * gv.x;  acc[1][1] += pv.y * gv.y;
        acc[1][2] += pv.y * gv.z;  acc[1][3] += pv.y * gv.w;
        acc[2][0] += pv.z * gv.x;  acc[2][1] += pv.z * gv.y;
        acc[2][2] += pv.z * gv.z;  acc[2][3] += pv.z * gv.w;
        acc[3][0] += pv.w * gv.x;  acc[3][1] += pv.w * gv.y;
        acc[3][2] += pv.w * gv.z;  acc[3][3] += pv.w * gv.w;
    }

    if (nok) {
        float* tb = Tp + (size_t)mc * TPSTR;
#pragma unroll
        for (int j = 0; j < 4; ++j) {
            int ko = ko0 + j;
            if (ko < KO) {
                float4 o4 = make_float4(acc[j][0], acc[j][1], acc[j][2], acc[j][3]);
                *reinterpret_cast<float4*>(&tb[(size_t)ko * LDIM + nb]) = o4;
            }
        }
    }
}

// ---------------------------------------------------------------------------
// K2: fold 4 partials (ko, pix) -> S[o][c*4096 + h*64 + w]
// One thread per output element (122880 threads, 480 blocks).
// ---------------------------------------------------------------------------
__global__ __launch_bounds__(256)
void fold_kernel(const float* __restrict__ Tp, float* __restrict__ S) {
    int idx = blockIdx.x * 256 + threadIdx.x;   // o*CHW + chw
    if (idx >= ODIM * CHW) return;
    int o   = idx / CHW;
    int chw = idx - o * CHW;
    int c = chw >> 12;
    int h = (chw >> 6) & 63;
    int w = chw & 63;

    float s = 0.f;
    for (int i = 0; i < 3; ++i) {
        int pi = h - i;
        if ((unsigned)pi >= HO) continue;
        for (int j = 0; j < 3; ++j) {
            int pj = w - j;
            if ((unsigned)pj >= HO) continue;
            int ko  = (c * 9 + i * 3 + j) * ODIM + o;
            size_t off = (size_t)ko * LDIM + pi * HO + pj;
#pragma unroll
            for (int p = 0; p < NPART; ++p)
                s += Tp[(size_t)p * TPSTR + off];
        }
    }
    S[idx] = s;
}

// ---------------------------------------------------------------------------
// K3: out[b][o] = sum_chw x[b][chw] * S[o][chw]; 2 images/block, 256 blocks.
// ---------------------------------------------------------------------------
__global__ __launch_bounds__(256)
void out_gemm_kernel(const float* __restrict__ X,
                     const float* __restrict__ S,
                     float* __restrict__ out) {
    const int b0  = blockIdx.x * 2;
    const int tid = threadIdx.x;
    const int NV  = CHW / 4;   // 3072
    const float4* X0 = reinterpret_cast<const float4*>(X) + (size_t)b0 * NV;
    const float4* X1 = X0 + NV;
    const float4* S4 = reinterpret_cast<const float4*>(S);

    float acc0[ODIM], acc1[ODIM];
#pragma unroll
    for (int o = 0; o < ODIM; ++o) { acc0[o] = 0.f; acc1[o] = 0.f; }

    for (int i = tid; i < NV; i += 256) {
        float4 a = X0[i];
        float4 b = X1[i];
#pragma unroll
        for (int o = 0; o < ODIM; ++o) {
            float4 sv = S4[(size_t)o * NV + i];
            acc0[o] += a.x * sv.x + a.y * sv.y + a.z * sv.z + a.w * sv.w;
            acc1[o] += b.x * sv.x + b.y * sv.y + b.z * sv.z + b.w * sv.w;
        }
    }

#pragma unroll
    for (int o = 0; o < ODIM; ++o) {
        float s0 = acc0[o], s1 = acc1[o];
        for (int off = 32; off > 0; off >>= 1) {
            s0 += __shfl_down(s0, off, 64);
            s1 += __shfl_down(s1, off, 64);
        }
        acc0[o] = s0; acc1[o] = s1;
    }

    __shared__ float red[4][2 * ODIM];
    int wave = tid >> 6;
    int lane = tid & 63;
    if (lane == 0) {
#pragma unroll
        for (int o = 0; o < ODIM; ++o) {
            red[wave][o] = acc0[o];
            red[wave][ODIM + o] = acc1[o];
        }
    }
    __syncthreads();
    if (tid < 2 * ODIM) {
        float tsum = red[0][tid] + red[1][tid] + red[2][tid] + red[3][tid];
        int bt = tid / ODIM;
        int o  = tid - bt * ODIM;
        out[(size_t)(b0 + bt) * ODIM + o] = tsum;
    }
}

extern "C" void kernel_launch(void* const* d_in, const int* in_sizes, int n_in,
                              void* d_out, int out_size, void* d_ws, size_t ws_size,
                              hipStream_t stream) {
    const float* x = (const float*)d_in[0];   // (512, 3, 64, 64)
    const float* G = (const float*)d_in[1];   // (512, 3844)
    const float* v = (const float*)d_in[2];   // (512, 27, 10)
    const float* w = (const float*)d_in[3];   // (512, 27, 10)
    float* out = (float*)d_out;               // (512, 10)

    float* Tp  = (float*)d_ws;                        // 4 * 270*3844 f = 16.6 MB
    float* S   = Tp + (size_t)NPART * TPSTR;          // 10*12288 f = 0.49 MB
    float* pdP = S + (size_t)ODIM * CHW;              // 512*272 f = 0.56 MB

    pd_kernel<<<(M_NEUR * KOP + 255) / 256, 256, 0, stream>>>(v, w, pdP);

    t_gemm_kernel<<<1088, 256, 0, stream>>>(G, pdP, Tp);

    fold_kernel<<<(ODIM * CHW + 255) / 256, 256, 0, stream>>>(Tp, S);

    out_gemm_kernel<<<BATCH / 2, 256, 0, stream>>>(x, S, out);
}